// Round 7
// baseline (234.182 us; speedup 1.0000x reference)
//
#include <hip/hip_runtime.h>
#include <hip/hip_bf16.h>
#include <stdint.h>

// ---------------- problem geometry ----------------
constexpr int L  = 2048;
constexpr int NB = 4;                 // batch
constexpr int E  = 1024;
constexpr int H  = 16;
constexpr int M  = L * NB;            // 8192 tokens
constexpr int K  = E;                 // 1024 (GEMM inner dim)
constexpr int QKV_LD = 3 * E;         // 3072

typedef float  f32x4  __attribute__((ext_vector_type(4)));
typedef __bf16 bf16x4 __attribute__((ext_vector_type(4)));
typedef __bf16 bf16x8 __attribute__((ext_vector_type(8)));

#define AS1 __attribute__((address_space(1)))
#define AS3 __attribute__((address_space(3)))

static __device__ __forceinline__ void gl_lds16(const void* g, void* l) {
  __builtin_amdgcn_global_load_lds((const AS1 uint32_t*)g, (AS3 uint32_t*)l, 16, 0, 0);
}

// =====================================================================
// fp32 -> bf16 bulk convert
// =====================================================================
__global__ __launch_bounds__(256)
void cvt_f32_bf16(const float* __restrict__ in, __bf16* __restrict__ out, int n4) {
  const int i = blockIdx.x * blockDim.x + threadIdx.x;
  if (i < n4) {
    const f32x4 v = ((const f32x4*)in)[i];
    bf16x4 o;
#pragma unroll
    for (int j = 0; j < 4; j++) o[j] = (__bf16)v[j];
    ((bf16x4*)out)[i] = o;
  }
}

// =====================================================================
// GEMM: C[M][NC] = A[M][K] * B[NC][K]^T  (bf16 in, fp32 accum, OutT out)
// =====================================================================
template<int NC, typename OutT>
__global__ __launch_bounds__(256)
void gemm_bt(const __bf16* __restrict__ A, const __bf16* __restrict__ B,
             OutT* __restrict__ C) {
  constexpr int BK = 64;
  __shared__ char lds[2 * 128 * BK * 2];
  char* aL = lds;
  char* bL = lds + 128 * BK * 2;

  const int t    = threadIdx.x;
  const int lane = t & 63;
  const int w    = t >> 6;
  const int g    = lane >> 4;
  const int c    = lane & 15;

  const int rowBase = blockIdx.y * 128;
  const int colBase = blockIdx.x * 128;

  const int srow = t >> 3;
  const int scb  = (t & 7) * 16;
  const int ssw  = scb ^ ((srow & 7) << 4);

  const char* aSrcBase = (const char*)(A + (size_t)(rowBase + srow) * K) + ssw;
  const char* bSrcBase = (const char*)(B + (size_t)(colBase + srow) * K) + ssw;

  f32x4 acc[4][4];
#pragma unroll
  for (int i = 0; i < 4; i++)
#pragma unroll
    for (int j = 0; j < 4; j++) acc[i][j] = f32x4{0.f, 0.f, 0.f, 0.f};

  const int wr = (w >> 1) * 64;
  const int wc = (w & 1) * 64;

  for (int k0 = 0; k0 < K; k0 += BK) {
    __syncthreads();
#pragma unroll
    for (int q = 0; q < 4; q++) {
      gl_lds16(aSrcBase + (size_t)2 * k0 + (size_t)q * 32 * K * 2, aL + q * 4096 + t * 16);
      gl_lds16(bSrcBase + (size_t)2 * k0 + (size_t)q * 32 * K * 2, bL + q * 4096 + t * 16);
    }
    __syncthreads();

    bf16x8 af[4][2], bfR[4][2];
#pragma unroll
    for (int mi = 0; mi < 4; mi++) {
      const int row = wr + mi * 16 + c;
      const int sw  = (row & 7) << 4;
#pragma unroll
      for (int ks = 0; ks < 2; ks++)
        af[mi][ks] = *(const bf16x8*)(aL + row * 128 + ((ks * 64 + g * 16) ^ sw));
    }
#pragma unroll
    for (int ni = 0; ni < 4; ni++) {
      const int row = wc + ni * 16 + c;
      const int sw  = (row & 7) << 4;
#pragma unroll
      for (int ks = 0; ks < 2; ks++)
        bfR[ni][ks] = *(const bf16x8*)(bL + row * 128 + ((ks * 64 + g * 16) ^ sw));
    }
#pragma unroll
    for (int mi = 0; mi < 4; mi++)
#pragma unroll
      for (int ni = 0; ni < 4; ni++)
#pragma unroll
        for (int ks = 0; ks < 2; ks++)
          acc[mi][ni] = __builtin_amdgcn_mfma_f32_16x16x32_bf16(
              af[mi][ks], bfR[ni][ks], acc[mi][ni], 0, 0, 0);
  }

#pragma unroll
  for (int mi = 0; mi < 4; mi++)
#pragma unroll
    for (int ni = 0; ni < 4; ni++)
#pragma unroll
      for (int r = 0; r < 4; r++) {
        const int row = rowBase + wr + mi * 16 + g * 4 + r;
        const int col = colBase + wc + ni * 16 + c;
        C[(size_t)row * NC + col] = (OutT)acc[mi][ni][r];
      }
}

// =====================================================================
// V transpose: qkv V-section [l][n][h*64+d] -> vT[(n*16+h)*64+d][l]
// =====================================================================
__global__ __launch_bounds__(256)
void transpose_v(const __bf16* __restrict__ qkv, __bf16* __restrict__ vT) {
  __shared__ char tile[64 * 160];     // elem(l,d) at l*160 + ((d*2) ^ (((l>>3)&7)<<4))
  const int lt = blockIdx.x;          // l-tile 0..31
  const int bh = blockIdx.y;          // n*16+h
  const int n  = bh >> 4, h = bh & 15;
  const int t  = threadIdx.x;
  const int r8 = t >> 3;              // 0..31
  const int c8 = (t & 7) * 8;         // 0..56

#pragma unroll
  for (int q2 = 0; q2 < 2; q2++) {
    const int l = q2 * 32 + r8;
    const bf16x8 v = *(const bf16x8*)(qkv + (size_t)((lt * 64 + l) * 4 + n) * QKV_LD +
                                      2 * E + h * 64 + c8);
    *(bf16x8*)(tile + l * 160 + ((c8 * 2) ^ (((l >> 3) & 7) << 4))) = v;
  }
  __syncthreads();
#pragma unroll
  for (int q2 = 0; q2 < 2; q2++) {
    const int d = q2 * 32 + r8;
    bf16x8 o;
#pragma unroll
    for (int i = 0; i < 8; i++) {
      const int l = c8 + i;
      o[i] = *(const __bf16*)(tile + l * 160 + ((d * 2) ^ (((l >> 3) & 7) << 4)));
    }
    *(bf16x8*)(vT + ((size_t)bh * 64 + d) * 2048 + lt * 64 + c8) = o;
  }
}

// =====================================================================
// Causal flash attention, 8-wave blocks sharing K/V staging.
// Block (qx,b): waves 0-3 compute q-tile qx, waves 4-7 q-tile 31-qx.
// kt ranges nest (qx <= 15 < 31-qx), so ONE staged K/V tile serves both;
// group A skips compute (wave-uniform) for kt > qx.
// Swapped QK^T (S^T via mfma(K,Q)): lane-local softmax, T13 defer-max.
// =====================================================================
__global__ __launch_bounds__(512, 8)
void attn_kernel(const __bf16* __restrict__ qkv, const __bf16* __restrict__ vT,
                 __bf16* __restrict__ out) {
  const int qx = blockIdx.x;            // 0..15
  const int b  = blockIdx.y;
  const int n  = b >> 4;
  const int h  = b & 15;

  __shared__ char kl[64 * 128];       // K tile [kv][d], swizzled (row&7)<<4
  __shared__ char vl[64 * 128];       // V^T tile [d][kv], swizzled (row&7)<<4
  __shared__ char pl[8][16 * 128];    // per-wave P [q16][kv64], swizzled

  const int t    = threadIdx.x;
  const int lane = t & 63;
  const int w    = t >> 6;            // 0..7
  const int g    = lane >> 4;
  const int c    = lane & 15;

  // staging: 512 threads cover one 64x128B tile per matrix (1 issue each)
  const int srow = t >> 3;            // 0..63
  const int scb  = (t & 7) * 16;
  const int kssw = scb ^ ((srow & 7) << 4);

  // scale = dh^-0.5 * log2(e): S in log2-units -> exp2 direct
  constexpr float QSCALE = 0.125f * 1.4426950408889634f;

  char* pw = pl[w];
  const int qloc = (w & 3) * 16 + c;  // lane's q row within its 64-tile
  const int qt   = (w < 4) ? qx : 31 - qx;   // per-wave q-tile
  const int ktEnd = 31 - qx;          // block loop bound (superset range)

  bf16x8 qa0, qa1;
  {
    const int qrow = qt * 64 + qloc;
    const __bf16* qp = qkv + (size_t)(qrow * 4 + n) * QKV_LD + h * 64;
    qa0 = *(const bf16x8*)(qp + g * 8);
    qa1 = *(const bf16x8*)(qp + 32 + g * 8);
#pragma unroll
    for (int i = 0; i < 8; i++) {
      qa0[i] = (__bf16)((float)qa0[i] * QSCALE);
      qa1[i] = (__bf16)((float)qa1[i] * QSCALE);
    }
  }

  float m_c = -3e38f, l_c = 0.f;      // per-lane softmax state for q = qloc
  f32x4 o[4];
#pragma unroll
  for (int ni = 0; ni < 4; ni++) o[ni] = f32x4{0.f, 0.f, 0.f, 0.f};

  for (int kt = 0; kt <= ktEnd; ++kt) {
    __syncthreads();
    // ---- stage K rows + V^T rows (shared by both wave groups) ----
    {
      const int kvrow = kt * 64 + srow;
      gl_lds16((const char*)(qkv + (size_t)(kvrow * 4 + n) * QKV_LD + E + h * 64) + kssw,
               kl + t * 16);
      gl_lds16((const char*)(vT + ((size_t)b * 64 + srow) * 2048 + kt * 64) + kssw,
               vl + t * 16);
    }
    __syncthreads();

    if (kt > qt) continue;            // wave-uniform: group A done staging only

    // ---- S^T = K (Q*qscale)^T : s[ni] rows kv=ni*16+g*4+r, col q=c ----
    f32x4 s[4];
#pragma unroll
    for (int ni = 0; ni < 4; ni++) s[ni] = f32x4{0.f, 0.f, 0.f, 0.f};
    __builtin_amdgcn_s_setprio(1);
#pragma unroll
    for (int ni = 0; ni < 4; ni++) {
      const int row = ni * 16 + c;
      const int sw  = (row & 7) << 4;
      const bf16x8 kb0 = *(const bf16x8*)(kl + row * 128 + ((g * 16) ^ sw));
      const bf16x8 kb1 = *(const bf16x8*)(kl + row * 128 + ((64 + g * 16) ^ sw));
      s[ni] = __builtin_amdgcn_mfma_f32_16x16x32_bf16(kb0, qa0, s[ni], 0, 0, 0);
      s[ni] = __builtin_amdgcn_mfma_f32_16x16x32_bf16(kb1, qa1, s[ni], 0, 0, 0);
    }
    __builtin_amdgcn_s_setprio(0);

    // ---- online softmax, lane-local row; T13 defer-max (THR=8) ----
    const bool lastTile = (kt == qt);
    float rmax = -3e38f;
#pragma unroll
    for (int ni = 0; ni < 4; ni++)
#pragma unroll
      for (int r = 0; r < 4; r++) {
        float v = s[ni][r];
        if (lastTile && (ni * 16 + g * 4 + r > qloc)) v = -3e38f;
        s[ni][r] = v;
        rmax = fmaxf(rmax, v);
      }
    rmax = fmaxf(rmax, __shfl_xor(rmax, 16));
    rmax = fmaxf(rmax, __shfl_xor(rmax, 32));

    if (__any(rmax > m_c + 8.f)) {    // rescale only on significant growth
      const float mnew  = fmaxf(m_c, rmax);
      const float alpha = exp2f(m_c - mnew);
      l_c *= alpha;
#pragma unroll
      for (int r = 0; r < 4; r++) {
        const float ar = __shfl(alpha, g * 4 + r);
#pragma unroll
        for (int ni = 0; ni < 4; ni++) o[ni][r] *= ar;
      }
      m_c = mnew;
    }

    float rsum = 0.f;
#pragma unroll
    for (int ni = 0; ni < 4; ni++)
#pragma unroll
      for (int r = 0; r < 4; r++) {
        const float e = exp2f(s[ni][r] - m_c);
        s[ni][r] = e;
        rsum += e;
      }
    rsum += __shfl_xor(rsum, 16);
    rsum += __shfl_xor(rsum, 32);
    l_c += rsum;

    // ---- P -> per-wave LDS: 4x packed ds_write_b64 (row q=c) ----
#pragma unroll
    for (int ni = 0; ni < 4; ni++) {
      bf16x4 pk;
#pragma unroll
      for (int r = 0; r < 4; r++) pk[r] = (__bf16)s[ni][r];
      *(bf16x4*)(pw + c * 128 + ((ni * 32 + g * 8) ^ ((c & 7) << 4))) = pk;
    }
    bf16x8 pa[2];
    {
      const int sw = (c & 7) << 4;
      pa[0] = *(const bf16x8*)(pw + c * 128 + ((g * 16) ^ sw));
      pa[1] = *(const bf16x8*)(pw + c * 128 + ((64 + g * 16) ^ sw));
    }
    // ---- O += P V ----
    __builtin_amdgcn_s_setprio(1);
#pragma unroll
    for (int ni = 0; ni < 4; ni++) {
      const int row = ni * 16 + c;
      const int sw  = (row & 7) << 4;
      const bf16x8 vb0 = *(const bf16x8*)(vl + row * 128 + ((g * 16) ^ sw));
      const bf16x8 vb1 = *(const bf16x8*)(vl + row * 128 + ((64 + g * 16) ^ sw));
      o[ni] = __builtin_amdgcn_mfma_f32_16x16x32_bf16(pa[0], vb0, o[ni], 0, 0, 0);
      o[ni] = __builtin_amdgcn_mfma_f32_16x16x32_bf16(pa[1], vb1, o[ni], 0, 0, 0);
    }
    __builtin_amdgcn_s_setprio(0);
  }

  // ---- epilogue: gather l for q=g*4+r, write O/l ----
#pragma unroll
  for (int r = 0; r < 4; r++) {
    const float lr   = __shfl(l_c, g * 4 + r);
    const float inv  = 1.f / lr;
    const int   qrow = qt * 64 + (w & 3) * 16 + g * 4 + r;
#pragma unroll
    for (int ni = 0; ni < 4; ni++) {
      const size_t off = (size_t)(qrow * 4 + n) * E + h * 64 + ni * 16 + c;
      out[off] = (__bf16)(o[ni][r] * inv);
    }
  }
}

// =====================================================================
extern "C" void kernel_launch(void* const* d_in, const int* in_sizes, int n_in,
                              void* d_out, int out_size, void* d_ws, size_t ws_size,
                              hipStream_t stream) {
  const float* x    = (const float*)d_in[0];
  const float* wqkv = (const float*)d_in[1];
  const float* wout = (const float*)d_in[2];

  char* ws = (char*)d_ws;
  __bf16* x_bf    = (__bf16*)ws;                         ws += (size_t)M * E * 2;       // 16 MB
  __bf16* wqkv_bf = (__bf16*)ws;                         ws += (size_t)QKV_LD * E * 2;  //  6 MB
  __bf16* wout_bf = (__bf16*)ws;                         ws += (size_t)E * E * 2;       //  2 MB
  __bf16* qkv     = (__bf16*)ws;                         ws += (size_t)M * QKV_LD * 2;  // 48 MB
  __bf16* attno   = (__bf16*)ws;                                                        // 16 MB
  __bf16* vT      = x_bf;   // x_bf dead after QKV GEMM; reuse as vT (16 MB)
  float*  outp    = (float*)d_out;

  cvt_f32_bf16<<<(M * E / 4) / 256, 256, 0, stream>>>(x, x_bf, M * E / 4);
  cvt_f32_bf16<<<(QKV_LD * E / 4) / 256, 256, 0, stream>>>(wqkv, wqkv_bf, QKV_LD * E / 4);
  cvt_f32_bf16<<<(E * E / 4) / 256, 256, 0, stream>>>(wout, wout_bf, E * E / 4);

  gemm_bt<QKV_LD, __bf16><<<dim3(QKV_LD / 128, M / 128), 256, 0, stream>>>(x_bf, wqkv_bf, qkv);
  transpose_v<<<dim3(L / 64, NB * H), 256, 0, stream>>>(qkv, vT);
  attn_kernel<<<dim3(16, NB * H), 512, 0, stream>>>(qkv, vT, attno);
  gemm_bt<E, float><<<dim3(E / 128, M / 128), 256, 0, stream>>>(attno, wout_bf, outp);
}

// Round 8
// 204.356 us; speedup vs baseline: 1.1460x; 1.1460x over previous
//
#include <hip/hip_runtime.h>
#include <hip/hip_bf16.h>
#include <stdint.h>

// ---------------- problem geometry ----------------
constexpr int L  = 2048;
constexpr int NB = 4;                 // batch
constexpr int E  = 1024;
constexpr int H  = 16;
constexpr int M  = L * NB;            // 8192 tokens
constexpr int K  = E;                 // 1024 (GEMM inner dim)
constexpr int QKV_LD = 3 * E;         // 3072

typedef float  f32x4  __attribute__((ext_vector_type(4)));
typedef __bf16 bf16x4 __attribute__((ext_vector_type(4)));
typedef __bf16 bf16x8 __attribute__((ext_vector_type(8)));

#define AS1 __attribute__((address_space(1)))
#define AS3 __attribute__((address_space(3)))

static __device__ __forceinline__ void gl_lds16(const void* g, void* l) {
  __builtin_amdgcn_global_load_lds((const AS1 uint32_t*)g, (AS3 uint32_t*)l, 16, 0, 0);
}

// =====================================================================
// fp32 -> bf16 bulk convert
// =====================================================================
__global__ __launch_bounds__(256)
void cvt_f32_bf16(const float* __restrict__ in, __bf16* __restrict__ out, int n4) {
  const int i = blockIdx.x * blockDim.x + threadIdx.x;
  if (i < n4) {
    const f32x4 v = ((const f32x4*)in)[i];
    bf16x4 o;
#pragma unroll
    for (int j = 0; j < 4; j++) o[j] = (__bf16)v[j];
    ((bf16x4*)out)[i] = o;
  }
}

// =====================================================================
// GEMM: C[M][NC] = A[M][K] * B[NC][K]^T  (bf16 in, fp32 accum, OutT out)
// =====================================================================
template<int NC, typename OutT>
__global__ __launch_bounds__(256)
void gemm_bt(const __bf16* __restrict__ A, const __bf16* __restrict__ B,
             OutT* __restrict__ C) {
  constexpr int BK = 64;
  __shared__ char lds[2 * 128 * BK * 2];
  char* aL = lds;
  char* bL = lds + 128 * BK * 2;

  const int t    = threadIdx.x;
  const int lane = t & 63;
  const int w    = t >> 6;
  const int g    = lane >> 4;
  const int c    = lane & 15;

  const int rowBase = blockIdx.y * 128;
  const int colBase = blockIdx.x * 128;

  const int srow = t >> 3;
  const int scb  = (t & 7) * 16;
  const int ssw  = scb ^ ((srow & 7) << 4);

  const char* aSrcBase = (const char*)(A + (size_t)(rowBase + srow) * K) + ssw;
  const char* bSrcBase = (const char*)(B + (size_t)(colBase + srow) * K) + ssw;

  f32x4 acc[4][4];
#pragma unroll
  for (int i = 0; i < 4; i++)
#pragma unroll
    for (int j = 0; j < 4; j++) acc[i][j] = f32x4{0.f, 0.f, 0.f, 0.f};

  const int wr = (w >> 1) * 64;
  const int wc = (w & 1) * 64;

  for (int k0 = 0; k0 < K; k0 += BK) {
    __syncthreads();
#pragma unroll
    for (int q = 0; q < 4; q++) {
      gl_lds16(aSrcBase + (size_t)2 * k0 + (size_t)q * 32 * K * 2, aL + q * 4096 + t * 16);
      gl_lds16(bSrcBase + (size_t)2 * k0 + (size_t)q * 32 * K * 2, bL + q * 4096 + t * 16);
    }
    __syncthreads();

    bf16x8 af[4][2], bfR[4][2];
#pragma unroll
    for (int mi = 0; mi < 4; mi++) {
      const int row = wr + mi * 16 + c;
      const int sw  = (row & 7) << 4;
#pragma unroll
      for (int ks = 0; ks < 2; ks++)
        af[mi][ks] = *(const bf16x8*)(aL + row * 128 + ((ks * 64 + g * 16) ^ sw));
    }
#pragma unroll
    for (int ni = 0; ni < 4; ni++) {
      const int row = wc + ni * 16 + c;
      const int sw  = (row & 7) << 4;
#pragma unroll
      for (int ks = 0; ks < 2; ks++)
        bfR[ni][ks] = *(const bf16x8*)(bL + row * 128 + ((ks * 64 + g * 16) ^ sw));
    }
#pragma unroll
    for (int mi = 0; mi < 4; mi++)
#pragma unroll
      for (int ni = 0; ni < 4; ni++)
#pragma unroll
        for (int ks = 0; ks < 2; ks++)
          acc[mi][ni] = __builtin_amdgcn_mfma_f32_16x16x32_bf16(
              af[mi][ks], bfR[ni][ks], acc[mi][ni], 0, 0, 0);
  }

#pragma unroll
  for (int mi = 0; mi < 4; mi++)
#pragma unroll
    for (int ni = 0; ni < 4; ni++)
#pragma unroll
      for (int r = 0; r < 4; r++) {
        const int row = rowBase + wr + mi * 16 + g * 4 + r;
        const int col = colBase + wc + ni * 16 + c;
        C[(size_t)row * NC + col] = (OutT)acc[mi][ni][r];
      }
}

// =====================================================================
// V transpose: qkv V-section [l][n][h*64+d] -> vT[(n*16+h)*64+d][l]
// =====================================================================
__global__ __launch_bounds__(256)
void transpose_v(const __bf16* __restrict__ qkv, __bf16* __restrict__ vT) {
  __shared__ char tile[64 * 160];     // elem(l,d) at l*160 + ((d*2) ^ (((l>>3)&7)<<4))
  const int lt = blockIdx.x;          // l-tile 0..31
  const int bh = blockIdx.y;          // n*16+h
  const int n  = bh >> 4, h = bh & 15;
  const int t  = threadIdx.x;
  const int r8 = t >> 3;              // 0..31
  const int c8 = (t & 7) * 8;         // 0..56

#pragma unroll
  for (int q2 = 0; q2 < 2; q2++) {
    const int l = q2 * 32 + r8;
    const bf16x8 v = *(const bf16x8*)(qkv + (size_t)((lt * 64 + l) * 4 + n) * QKV_LD +
                                      2 * E + h * 64 + c8);
    *(bf16x8*)(tile + l * 160 + ((c8 * 2) ^ (((l >> 3) & 7) << 4))) = v;
  }
  __syncthreads();
#pragma unroll
  for (int q2 = 0; q2 < 2; q2++) {
    const int d = q2 * 32 + r8;
    bf16x8 o;
#pragma unroll
    for (int i = 0; i < 8; i++) {
      const int l = c8 + i;
      o[i] = *(const __bf16*)(tile + l * 160 + ((d * 2) ^ (((l >> 3) & 7) << 4)));
    }
    *(bf16x8*)(vT + ((size_t)bh * 64 + d) * 2048 + lt * 64 + c8) = o;
  }
}

// =====================================================================
// Causal flash attention. Balanced: block (qx,b) does q-tiles {qx,31-qx}
// sequentially (round-6 validated structure, 256 threads / 4 waves).
// NEW: double-buffered K/V with 2-phase pipeline — per iteration:
//   barrier -> issue stage(kt+1 -> buf^1) -> compute(buf) -> flip.
// The compiler's vmcnt(0) drain before the next barrier lands AFTER the
// compute phase, hiding the HBM/L2 latency; one barrier per tile.
// Swapped QK^T (S^T = mfma(K,Q)): lane-local softmax, T13 defer-max.
// =====================================================================
__global__ __launch_bounds__(256)
void attn_kernel(const __bf16* __restrict__ qkv, const __bf16* __restrict__ vT,
                 __bf16* __restrict__ out) {
  const int qx = blockIdx.x;            // 0..15
  const int b  = blockIdx.y;
  const int n  = b >> 4;
  const int h  = b & 15;

  __shared__ char kl[2][64 * 128];    // K tiles [kv][d], swizzled (row&7)<<4
  __shared__ char vl[2][64 * 128];    // V^T tiles [d][kv], swizzled
  __shared__ char pl[4][16 * 128];    // per-wave P [q16][kv64], swizzled

  const int t    = threadIdx.x;
  const int lane = t & 63;
  const int w    = t >> 6;
  const int g    = lane >> 4;
  const int c    = lane & 15;

  const int srow = t >> 3;            // 0..31
  const int scb  = (t & 7) * 16;
  const int kssw = scb ^ ((srow & 7) << 4);

  // scale = dh^-0.5 * log2(e): S in log2-units -> exp2 direct
  constexpr float QSCALE = 0.125f * 1.4426950408889634f;

  char* pw = pl[w];
  const int qloc = w * 16 + c;        // lane's q row within the 64-tile

  int cur = 0;

  for (int pass = 0; pass < 2; ++pass) {
    const int qt = pass ? 31 - qx : qx;

    bf16x8 qa0, qa1;
    {
      const int qrow = qt * 64 + qloc;
      const __bf16* qp = qkv + (size_t)(qrow * 4 + n) * QKV_LD + h * 64;
      qa0 = *(const bf16x8*)(qp + g * 8);
      qa1 = *(const bf16x8*)(qp + 32 + g * 8);
#pragma unroll
      for (int i = 0; i < 8; i++) {
        qa0[i] = (__bf16)((float)qa0[i] * QSCALE);
        qa1[i] = (__bf16)((float)qa1[i] * QSCALE);
      }
    }

    float m_c = -3e38f, l_c = 0.f;    // per-lane softmax state for q = qloc
    f32x4 o[4];
#pragma unroll
    for (int ni = 0; ni < 4; ni++) o[ni] = f32x4{0.f, 0.f, 0.f, 0.f};

    // prologue: issue tile kt=0 into buf[cur]
    // (safe: target buffer's last readers are sealed by a prior barrier)
#pragma unroll
    for (int q2 = 0; q2 < 2; q2++) {
      const int kvrow = q2 * 32 + srow;
      gl_lds16((const char*)(qkv + (size_t)(kvrow * 4 + n) * QKV_LD + E + h * 64) + kssw,
               kl[cur] + q2 * 4096 + t * 16);
      gl_lds16((const char*)(vT + ((size_t)b * 64 + q2 * 32 + srow) * 2048) + kssw,
               vl[cur] + q2 * 4096 + t * 16);
    }

    for (int kt = 0; kt <= qt; ++kt) {
      __syncthreads();                // drains vmcnt -> buf[cur] ready

      // ---- issue prefetch of tile kt+1 into buf[cur^1] ----
      if (kt < qt) {
        const int nx = kt + 1;
#pragma unroll
        for (int q2 = 0; q2 < 2; q2++) {
          const int kvrow = nx * 64 + q2 * 32 + srow;
          gl_lds16((const char*)(qkv + (size_t)(kvrow * 4 + n) * QKV_LD + E + h * 64) + kssw,
                   kl[cur ^ 1] + q2 * 4096 + t * 16);
          const int vd = q2 * 32 + srow;
          gl_lds16((const char*)(vT + ((size_t)b * 64 + vd) * 2048 + nx * 64) + kssw,
                   vl[cur ^ 1] + q2 * 4096 + t * 16);
        }
      }
      __builtin_amdgcn_sched_barrier(0);   // pin issue-early order

      const char* klc = kl[cur];
      const char* vlc = vl[cur];

      // ---- S^T = K (Q*qscale)^T : s[ni] rows kv=ni*16+g*4+r, col q=c ----
      f32x4 s[4];
#pragma unroll
      for (int ni = 0; ni < 4; ni++) s[ni] = f32x4{0.f, 0.f, 0.f, 0.f};
      __builtin_amdgcn_s_setprio(1);
#pragma unroll
      for (int ni = 0; ni < 4; ni++) {
        const int row = ni * 16 + c;
        const int sw  = (row & 7) << 4;
        const bf16x8 kb0 = *(const bf16x8*)(klc + row * 128 + ((g * 16) ^ sw));
        const bf16x8 kb1 = *(const bf16x8*)(klc + row * 128 + ((64 + g * 16) ^ sw));
        s[ni] = __builtin_amdgcn_mfma_f32_16x16x32_bf16(kb0, qa0, s[ni], 0, 0, 0);
        s[ni] = __builtin_amdgcn_mfma_f32_16x16x32_bf16(kb1, qa1, s[ni], 0, 0, 0);
      }
      __builtin_amdgcn_s_setprio(0);

      // ---- online softmax, lane-local row; T13 defer-max (THR=8) ----
      const bool lastTile = (kt == qt);
      float rmax = -3e38f;
#pragma unroll
      for (int ni = 0; ni < 4; ni++)
#pragma unroll
        for (int r = 0; r < 4; r++) {
          float v = s[ni][r];
          if (lastTile && (ni * 16 + g * 4 + r > qloc)) v = -3e38f;
          s[ni][r] = v;
          rmax = fmaxf(rmax, v);
        }
      rmax = fmaxf(rmax, __shfl_xor(rmax, 16));
      rmax = fmaxf(rmax, __shfl_xor(rmax, 32));

      if (__any(rmax > m_c + 8.f)) {  // rescale only on significant growth
        const float mnew  = fmaxf(m_c, rmax);
        const float alpha = exp2f(m_c - mnew);
        l_c *= alpha;
#pragma unroll
        for (int r = 0; r < 4; r++) {
          const float ar = __shfl(alpha, g * 4 + r);
#pragma unroll
          for (int ni = 0; ni < 4; ni++) o[ni][r] *= ar;
        }
        m_c = mnew;
      }

      float rsum = 0.f;
#pragma unroll
      for (int ni = 0; ni < 4; ni++)
#pragma unroll
        for (int r = 0; r < 4; r++) {
          const float e = exp2f(s[ni][r] - m_c);
          s[ni][r] = e;
          rsum += e;
        }
      rsum += __shfl_xor(rsum, 16);
      rsum += __shfl_xor(rsum, 32);
      l_c += rsum;

      // ---- P -> per-wave LDS: 4x packed ds_write_b64 (row q=c) ----
#pragma unroll
      for (int ni = 0; ni < 4; ni++) {
        bf16x4 pk;
#pragma unroll
        for (int r = 0; r < 4; r++) pk[r] = (__bf16)s[ni][r];
        *(bf16x4*)(pw + c * 128 + ((ni * 32 + g * 8) ^ ((c & 7) << 4))) = pk;
      }
      bf16x8 pa[2];
      {
        const int sw = (c & 7) << 4;
        pa[0] = *(const bf16x8*)(pw + c * 128 + ((g * 16) ^ sw));
        pa[1] = *(const bf16x8*)(pw + c * 128 + ((64 + g * 16) ^ sw));
      }
      // ---- O += P V ----
      __builtin_amdgcn_s_setprio(1);
#pragma unroll
      for (int ni = 0; ni < 4; ni++) {
        const int row = ni * 16 + c;
        const int sw  = (row & 7) << 4;
        const bf16x8 vb0 = *(const bf16x8*)(vlc + row * 128 + ((g * 16) ^ sw));
        const bf16x8 vb1 = *(const bf16x8*)(vlc + row * 128 + ((64 + g * 16) ^ sw));
        o[ni] = __builtin_amdgcn_mfma_f32_16x16x32_bf16(pa[0], vb0, o[ni], 0, 0, 0);
        o[ni] = __builtin_amdgcn_mfma_f32_16x16x32_bf16(pa[1], vb1, o[ni], 0, 0, 0);
      }
      __builtin_amdgcn_s_setprio(0);

      cur ^= 1;
    }

    // ---- epilogue: gather l for q=g*4+r, write O/l ----
#pragma unroll
    for (int r = 0; r < 4; r++) {
      const float lr   = __shfl(l_c, g * 4 + r);
      const float inv  = 1.f / lr;
      const int   qrow = qt * 64 + w * 16 + g * 4 + r;
#pragma unroll
      for (int ni = 0; ni < 4; ni++) {
        const size_t off = (size_t)(qrow * 4 + n) * E + h * 64 + ni * 16 + c;
        out[off] = (__bf16)(o[ni][r] * inv);
      }
    }
  }
}

// =====================================================================
extern "C" void kernel_launch(void* const* d_in, const int* in_sizes, int n_in,
                              void* d_out, int out_size, void* d_ws, size_t ws_size,
                              hipStream_t stream) {
  const float* x    = (const float*)d_in[0];
  const float* wqkv = (const float*)d_in[1];
  const float* wout = (const float*)d_in[2];

  char* ws = (char*)d_ws;
  __bf16* x_bf    = (__bf16*)ws;                         ws += (size_t)M * E * 2;       // 16 MB
  __bf16* wqkv_bf = (__bf16*)ws;                         ws += (size_t)QKV_LD * E * 2;  //  6 MB
  __bf16* wout_bf = (__bf16*)ws;                         ws += (size_t)E * E * 2;       //  2 MB
  __bf16* qkv     = (__bf16*)ws;                         ws += (size_t)M * QKV_LD * 2;  // 48 MB
  __bf16* attno   = (__bf16*)ws;                                                        // 16 MB
  __bf16* vT      = x_bf;   // x_bf dead after QKV GEMM; reuse as vT (16 MB)
  float*  outp    = (float*)d_out;

  cvt_f32_bf16<<<(M * E / 4) / 256, 256, 0, stream>>>(x, x_bf, M * E / 4);
  cvt_f32_bf16<<<(QKV_LD * E / 4) / 256, 256, 0, stream>>>(wqkv, wqkv_bf, QKV_LD * E / 4);
  cvt_f32_bf16<<<(E * E / 4) / 256, 256, 0, stream>>>(wout, wout_bf, E * E / 4);

  gemm_bt<QKV_LD, __bf16><<<dim3(QKV_LD / 128, M / 128), 256, 0, stream>>>(x_bf, wqkv_bf, qkv);
  transpose_v<<<dim3(L / 64, NB * H), 256, 0, stream>>>(qkv, vT);
  attn_kernel<<<dim3(16, NB * H), 256, 0, stream>>>(qkv, vT, attno);
  gemm_bt<E, float><<<dim3(E / 128, M / 128), 256, 0, stream>>>(attno, wout_bf, outp);
}

// Round 9
// 196.002 us; speedup vs baseline: 1.1948x; 1.0426x over previous
//
#include <hip/hip_runtime.h>
#include <hip/hip_bf16.h>
#include <stdint.h>

// ---------------- problem geometry ----------------
constexpr int L  = 2048;
constexpr int NB = 4;                 // batch
constexpr int E  = 1024;
constexpr int H  = 16;
constexpr int M  = L * NB;            // 8192 tokens
constexpr int K  = E;                 // 1024 (GEMM inner dim)
constexpr int QKV_LD = 3 * E;         // 3072

typedef float  f32x4  __attribute__((ext_vector_type(4)));
typedef __bf16 bf16x4 __attribute__((ext_vector_type(4)));
typedef __bf16 bf16x8 __attribute__((ext_vector_type(8)));

#define AS1 __attribute__((address_space(1)))
#define AS3 __attribute__((address_space(3)))

static __device__ __forceinline__ void gl_lds16(const void* g, void* l) {
  __builtin_amdgcn_global_load_lds((const AS1 uint32_t*)g, (AS3 uint32_t*)l, 16, 0, 0);
}

// =====================================================================
// fp32 -> bf16 bulk convert
// =====================================================================
__global__ __launch_bounds__(256)
void cvt_f32_bf16(const float* __restrict__ in, __bf16* __restrict__ out, int n4) {
  const int i = blockIdx.x * blockDim.x + threadIdx.x;
  if (i < n4) {
    const f32x4 v = ((const f32x4*)in)[i];
    bf16x4 o;
#pragma unroll
    for (int j = 0; j < 4; j++) o[j] = (__bf16)v[j];
    ((bf16x4*)out)[i] = o;
  }
}

// =====================================================================
// GEMM: C[M][NC] = A[M][K] * B[NC][K]^T  (bf16 in, fp32 accum, OutT out)
// T1: bijective XCD swizzle (nwg divisible by 8 for both instantiations)
// =====================================================================
template<int NC, typename OutT>
__global__ __launch_bounds__(256)
void gemm_bt(const __bf16* __restrict__ A, const __bf16* __restrict__ B,
             OutT* __restrict__ C) {
  constexpr int BK = 64;
  __shared__ char lds[2 * 128 * BK * 2];
  char* aL = lds;
  char* bL = lds + 128 * BK * 2;

  const int t    = threadIdx.x;
  const int lane = t & 63;
  const int w    = t >> 6;
  const int g    = lane >> 4;
  const int c    = lane & 15;

  // XCD-aware swizzle: each XCD gets a contiguous chunk of wgids
  const int nwg = gridDim.x * gridDim.y;
  const int lin = blockIdx.x + gridDim.x * blockIdx.y;
  const int q8  = nwg >> 3;
  const int swz = (lin & 7) * q8 + (lin >> 3);
  const int bx  = swz % gridDim.x;
  const int by  = swz / gridDim.x;

  const int rowBase = by * 128;
  const int colBase = bx * 128;

  const int srow = t >> 3;
  const int scb  = (t & 7) * 16;
  const int ssw  = scb ^ ((srow & 7) << 4);

  const char* aSrcBase = (const char*)(A + (size_t)(rowBase + srow) * K) + ssw;
  const char* bSrcBase = (const char*)(B + (size_t)(colBase + srow) * K) + ssw;

  f32x4 acc[4][4];
#pragma unroll
  for (int i = 0; i < 4; i++)
#pragma unroll
    for (int j = 0; j < 4; j++) acc[i][j] = f32x4{0.f, 0.f, 0.f, 0.f};

  const int wr = (w >> 1) * 64;
  const int wc = (w & 1) * 64;

  for (int k0 = 0; k0 < K; k0 += BK) {
    __syncthreads();
#pragma unroll
    for (int q = 0; q < 4; q++) {
      gl_lds16(aSrcBase + (size_t)2 * k0 + (size_t)q * 32 * K * 2, aL + q * 4096 + t * 16);
      gl_lds16(bSrcBase + (size_t)2 * k0 + (size_t)q * 32 * K * 2, bL + q * 4096 + t * 16);
    }
    __syncthreads();

    bf16x8 af[4][2], bfR[4][2];
#pragma unroll
    for (int mi = 0; mi < 4; mi++) {
      const int row = wr + mi * 16 + c;
      const int sw  = (row & 7) << 4;
#pragma unroll
      for (int ks = 0; ks < 2; ks++)
        af[mi][ks] = *(const bf16x8*)(aL + row * 128 + ((ks * 64 + g * 16) ^ sw));
    }
#pragma unroll
    for (int ni = 0; ni < 4; ni++) {
      const int row = wc + ni * 16 + c;
      const int sw  = (row & 7) << 4;
#pragma unroll
      for (int ks = 0; ks < 2; ks++)
        bfR[ni][ks] = *(const bf16x8*)(bL + row * 128 + ((ks * 64 + g * 16) ^ sw));
    }
#pragma unroll
    for (int mi = 0; mi < 4; mi++)
#pragma unroll
      for (int ni = 0; ni < 4; ni++)
#pragma unroll
        for (int ks = 0; ks < 2; ks++)
          acc[mi][ni] = __builtin_amdgcn_mfma_f32_16x16x32_bf16(
              af[mi][ks], bfR[ni][ks], acc[mi][ni], 0, 0, 0);
  }

#pragma unroll
  for (int mi = 0; mi < 4; mi++)
#pragma unroll
    for (int ni = 0; ni < 4; ni++)
#pragma unroll
      for (int r = 0; r < 4; r++) {
        const int row = rowBase + wr + mi * 16 + g * 4 + r;
        const int col = colBase + wc + ni * 16 + c;
        C[(size_t)row * NC + col] = (OutT)acc[mi][ni][r];
      }
}

// =====================================================================
// V transpose: qkv V-section [l][n][h*64+d] -> vT[(n*16+h)*64+d][l]
// =====================================================================
__global__ __launch_bounds__(256)
void transpose_v(const __bf16* __restrict__ qkv, __bf16* __restrict__ vT) {
  __shared__ char tile[64 * 160];     // elem(l,d) at l*160 + ((d*2) ^ (((l>>3)&7)<<4))
  const int lt = blockIdx.x;          // l-tile 0..31
  const int bh = blockIdx.y;          // n*16+h
  const int n  = bh >> 4, h = bh & 15;
  const int t  = threadIdx.x;
  const int r8 = t >> 3;              // 0..31
  const int c8 = (t & 7) * 8;         // 0..56

#pragma unroll
  for (int q2 = 0; q2 < 2; q2++) {
    const int l = q2 * 32 + r8;
    const bf16x8 v = *(const bf16x8*)(qkv + (size_t)((lt * 64 + l) * 4 + n) * QKV_LD +
                                      2 * E + h * 64 + c8);
    *(bf16x8*)(tile + l * 160 + ((c8 * 2) ^ (((l >> 3) & 7) << 4))) = v;
  }
  __syncthreads();
#pragma unroll
  for (int q2 = 0; q2 < 2; q2++) {
    const int d = q2 * 32 + r8;
    bf16x8 o;
#pragma unroll
    for (int i = 0; i < 8; i++) {
      const int l = c8 + i;
      o[i] = *(const __bf16*)(tile + l * 160 + ((d * 2) ^ (((l >> 3) & 7) << 4)));
    }
    *(bf16x8*)(vT + ((size_t)bh * 64 + d) * 2048 + lt * 64 + c8) = o;
  }
}

// =====================================================================
// Causal flash attention (r8 validated structure + mask hoist + L2 grid).
// grid (64,16): x = b (head-batch), y = qx -> XCD = b%8, so one XCD's
// resident blocks share 8 heads' K/V = 4 MB = its L2.
// Block does q-tiles {qx, 31-qx}; double-buffered K/V staging; swapped
// QK^T; lane-local softmax; masking applied only on diagonal tile.
// =====================================================================
__global__ __launch_bounds__(256)
void attn_kernel(const __bf16* __restrict__ qkv, const __bf16* __restrict__ vT,
                 __bf16* __restrict__ out) {
  const int b  = blockIdx.x;            // 0..63 (n*16+h)
  const int qx = blockIdx.y;            // 0..15
  const int n  = b >> 4;
  const int h  = b & 15;

  __shared__ char kl[2][64 * 128];    // K tiles [kv][d], swizzled (row&7)<<4
  __shared__ char vl[2][64 * 128];    // V^T tiles [d][kv], swizzled
  __shared__ char pl[4][16 * 128];    // per-wave P [q16][kv64], swizzled

  const int t    = threadIdx.x;
  const int lane = t & 63;
  const int w    = t >> 6;
  const int g    = lane >> 4;
  const int c    = lane & 15;

  const int srow = t >> 3;            // 0..31
  const int scb  = (t & 7) * 16;
  const int kssw = scb ^ ((srow & 7) << 4);

  // scale = dh^-0.5 * log2(e): S in log2-units -> exp2 direct
  constexpr float QSCALE = 0.125f * 1.4426950408889634f;

  char* pw = pl[w];
  const int qloc = w * 16 + c;        // lane's q row within the 64-tile

  int cur = 0;

  for (int pass = 0; pass < 2; ++pass) {
    const int qt = pass ? 31 - qx : qx;

    bf16x8 qa0, qa1;
    {
      const int qrow = qt * 64 + qloc;
      const __bf16* qp = qkv + (size_t)(qrow * 4 + n) * QKV_LD + h * 64;
      qa0 = *(const bf16x8*)(qp + g * 8);
      qa1 = *(const bf16x8*)(qp + 32 + g * 8);
#pragma unroll
      for (int i = 0; i < 8; i++) {
        qa0[i] = (__bf16)((float)qa0[i] * QSCALE);
        qa1[i] = (__bf16)((float)qa1[i] * QSCALE);
      }
    }

    float m_c = -3e38f, l_c = 0.f;    // per-lane softmax state for q = qloc
    f32x4 o[4];
#pragma unroll
    for (int ni = 0; ni < 4; ni++) o[ni] = f32x4{0.f, 0.f, 0.f, 0.f};

    // prologue (pass 0 only): issue tile kt=0 into buf[cur]; pass 1's
    // first tile is prefetched during pass 0's diagonal iteration.
    if (pass == 0) {
#pragma unroll
      for (int q2 = 0; q2 < 2; q2++) {
        const int kvrow = q2 * 32 + srow;
        gl_lds16((const char*)(qkv + (size_t)(kvrow * 4 + n) * QKV_LD + E + h * 64) + kssw,
                 kl[cur] + q2 * 4096 + t * 16);
        gl_lds16((const char*)(vT + ((size_t)b * 64 + q2 * 32 + srow) * 2048) + kssw,
                 vl[cur] + q2 * 4096 + t * 16);
      }
    }

    for (int kt = 0; kt <= qt; ++kt) {
      __syncthreads();                // drains vmcnt -> buf[cur] ready

      // ---- issue prefetch of the next needed tile into buf[cur^1] ----
      // main loop: tile kt+1 of this pass; diagonal iter of pass 0:
      // tile 0 of pass 1. (Target buffer's readers sealed by barrier.)
      const bool lastTile = (kt == qt);
      if (!lastTile || pass == 0) {
        const int nx = lastTile ? 0 : kt + 1;
#pragma unroll
        for (int q2 = 0; q2 < 2; q2++) {
          const int kvrow = nx * 64 + q2 * 32 + srow;
          gl_lds16((const char*)(qkv + (size_t)(kvrow * 4 + n) * QKV_LD + E + h * 64) + kssw,
                   kl[cur ^ 1] + q2 * 4096 + t * 16);
          const int vd = q2 * 32 + srow;
          gl_lds16((const char*)(vT + ((size_t)b * 64 + vd) * 2048 + nx * 64) + kssw,
                   vl[cur ^ 1] + q2 * 4096 + t * 16);
        }
      }
      __builtin_amdgcn_sched_barrier(0);   // pin issue-early order

      const char* klc = kl[cur];
      const char* vlc = vl[cur];

      // ---- S^T = K (Q*qscale)^T : s[ni] rows kv=ni*16+g*4+r, col q=c ----
      f32x4 s[4];
#pragma unroll
      for (int ni = 0; ni < 4; ni++) s[ni] = f32x4{0.f, 0.f, 0.f, 0.f};
      __builtin_amdgcn_s_setprio(1);
#pragma unroll
      for (int ni = 0; ni < 4; ni++) {
        const int row = ni * 16 + c;
        const int sw  = (row & 7) << 4;
        const bf16x8 kb0 = *(const bf16x8*)(klc + row * 128 + ((g * 16) ^ sw));
        const bf16x8 kb1 = *(const bf16x8*)(klc + row * 128 + ((64 + g * 16) ^ sw));
        s[ni] = __builtin_amdgcn_mfma_f32_16x16x32_bf16(kb0, qa0, s[ni], 0, 0, 0);
        s[ni] = __builtin_amdgcn_mfma_f32_16x16x32_bf16(kb1, qa1, s[ni], 0, 0, 0);
      }
      __builtin_amdgcn_s_setprio(0);

      // ---- causal mask: diagonal tile ONLY (wave-uniform branch) ----
      if (lastTile) {
#pragma unroll
        for (int ni = 0; ni < 4; ni++)
#pragma unroll
          for (int r = 0; r < 4; r++)
            if (ni * 16 + g * 4 + r > qloc) s[ni][r] = -3e38f;
      }

      // ---- online softmax, lane-local row; T13 defer-max (THR=8) ----
      float rmax = -3e38f;
#pragma unroll
      for (int ni = 0; ni < 4; ni++)
#pragma unroll
        for (int r = 0; r < 4; r++) rmax = fmaxf(rmax, s[ni][r]);
      rmax = fmaxf(rmax, __shfl_xor(rmax, 16));
      rmax = fmaxf(rmax, __shfl_xor(rmax, 32));

      if (__any(rmax > m_c + 8.f)) {  // rescale only on significant growth
        const float mnew  = fmaxf(m_c, rmax);
        const float alpha = exp2f(m_c - mnew);
        l_c *= alpha;
#pragma unroll
        for (int r = 0; r < 4; r++) {
          const float ar = __shfl(alpha, g * 4 + r);
#pragma unroll
          for (int ni = 0; ni < 4; ni++) o[ni][r] *= ar;
        }
        m_c = mnew;
      }

      float rsum = 0.f;
#pragma unroll
      for (int ni = 0; ni < 4; ni++)
#pragma unroll
        for (int r = 0; r < 4; r++) {
          const float e = exp2f(s[ni][r] - m_c);
          s[ni][r] = e;
          rsum += e;
        }
      rsum += __shfl_xor(rsum, 16);
      rsum += __shfl_xor(rsum, 32);
      l_c += rsum;

      // ---- P -> per-wave LDS: 4x packed ds_write_b64 (row q=c) ----
#pragma unroll
      for (int ni = 0; ni < 4; ni++) {
        bf16x4 pk;
#pragma unroll
        for (int r = 0; r < 4; r++) pk[r] = (__bf16)s[ni][r];
        *(bf16x4*)(pw + c * 128 + ((ni * 32 + g * 8) ^ ((c & 7) << 4))) = pk;
      }
      bf16x8 pa[2];
      {
        const int sw = (c & 7) << 4;
        pa[0] = *(const bf16x8*)(pw + c * 128 + ((g * 16) ^ sw));
        pa[1] = *(const bf16x8*)(pw + c * 128 + ((64 + g * 16) ^ sw));
      }
      // ---- O += P V ----
      __builtin_amdgcn_s_setprio(1);
#pragma unroll
      for (int ni = 0; ni < 4; ni++) {
        const int row = ni * 16 + c;
        const int sw  = (row & 7) << 4;
        const bf16x8 vb0 = *(const bf16x8*)(vlc + row * 128 + ((g * 16) ^ sw));
        const bf16x8 vb1 = *(const bf16x8*)(vlc + row * 128 + ((64 + g * 16) ^ sw));
        o[ni] = __builtin_amdgcn_mfma_f32_16x16x32_bf16(pa[0], vb0, o[ni], 0, 0, 0);
        o[ni] = __builtin_amdgcn_mfma_f32_16x16x32_bf16(pa[1], vb1, o[ni], 0, 0, 0);
      }
      __builtin_amdgcn_s_setprio(0);

      cur ^= 1;
    }

    // ---- epilogue: gather l for q=g*4+r, write O/l ----
#pragma unroll
    for (int r = 0; r < 4; r++) {
      const float lr   = __shfl(l_c, g * 4 + r);
      const float inv  = 1.f / lr;
      const int   qrow = qt * 64 + w * 16 + g * 4 + r;
#pragma unroll
      for (int ni = 0; ni < 4; ni++) {
        const size_t off = (size_t)(qrow * 4 + n) * E + h * 64 + ni * 16 + c;
        out[off] = (__bf16)(o[ni][r] * inv);
      }
    }
  }
}

// =====================================================================
extern "C" void kernel_launch(void* const* d_in, const int* in_sizes, int n_in,
                              void* d_out, int out_size, void* d_ws, size_t ws_size,
                              hipStream_t stream) {
  const float* x    = (const float*)d_in[0];
  const float* wqkv = (const float*)d_in[1];
  const float* wout = (const float*)d_in[2];

  char* ws = (char*)d_ws;
  __bf16* x_bf    = (__bf16*)ws;                         ws += (size_t)M * E * 2;       // 16 MB
  __bf16* wqkv_bf = (__bf16*)ws;                         ws += (size_t)QKV_LD * E * 2;  //  6 MB
  __bf16* wout_bf = (__bf16*)ws;                         ws += (size_t)E * E * 2;       //  2 MB
  __bf16* qkv     = (__bf16*)ws;                         ws += (size_t)M * QKV_LD * 2;  // 48 MB
  __bf16* attno   = (__bf16*)ws;                                                        // 16 MB
  __bf16* vT      = x_bf;   // x_bf dead after QKV GEMM; reuse as vT (16 MB)
  float*  outp    = (float*)d_out;

  cvt_f32_bf16<<<(M * E / 4) / 256, 256, 0, stream>>>(x, x_bf, M * E / 4);
  cvt_f32_bf16<<<(QKV_LD * E / 4) / 256, 256, 0, stream>>>(wqkv, wqkv_bf, QKV_LD * E / 4);
  cvt_f32_bf16<<<(E * E / 4) / 256, 256, 0, stream>>>(wout, wout_bf, E * E / 4);

  gemm_bt<QKV_LD, __bf16><<<dim3(QKV_LD / 128, M / 128), 256, 0, stream>>>(x_bf, wqkv_bf, qkv);
  transpose_v<<<dim3(L / 64, NB * H), 256, 0, stream>>>(qkv, vT);
  attn_kernel<<<dim3(NB * H, 16), 256, 0, stream>>>(qkv, vT, attno);
  gemm_bt<E, float><<<dim3(E / 128, M / 128), 256, 0, stream>>>(attno, wout_bf, outp);
}